// Round 1
// baseline (489.243 us; speedup 1.0000x reference)
//
#include <hip/hip_runtime.h>
#include <math.h>

// Problem constants (fixed by the reference)
constexpr int Bn   = 1024;  // batch
constexpr int DH   = 2048;  // half input width (sbj/obj)
constexpr int K1   = 4096;  // concat width
constexpr int DO   = 1024;  // hidden / output width
constexpr int NL   = 128;   // labels

constexpr int BM = 64, BN = 64, BK = 16;

// Tiled fp32 GEMM: out[M,N] = act(A) @ W + bias (+optional relu on output).
// CONCAT_RELU_IN: A is concat(relu(sbj),relu(obj)) materialized on the fly.
// Block: 256 threads, 64x64 tile, 4x4 micro-tile per thread.
template <bool CONCAT_RELU_IN, bool RELU_OUT>
__global__ __launch_bounds__(256)
void gemm_kernel(const float* __restrict__ A0, const float* __restrict__ A1,
                 const float* __restrict__ W,  const float* __restrict__ bias,
                 float* __restrict__ out, int M, int N, int K)
{
    __shared__ __align__(16) float As[BK][BM + 4];  // [k][m], pad keeps 16B align, 2-way banks (free)
    __shared__ __align__(16) float Bs[BK][BN + 4];  // [k][n]

    const int tid = threadIdx.x;
    const int tx  = tid & 15;   // micro col group
    const int ty  = tid >> 4;   // micro row group
    const int row0 = blockIdx.y * BM;
    const int col0 = blockIdx.x * BN;

    float acc[4][4] = {};

    for (int k0 = 0; k0 < K; k0 += BK) {
        // --- stage A tile (BM x BK), transposed into As[k][m] ---
        #pragma unroll
        for (int i = 0; i < 4; ++i) {
            const int r  = (tid >> 4) + i * 16;  // 0..63 (m)
            const int c  = tid & 15;             // 0..15 (k)
            const int gr = row0 + r;
            const int gk = k0 + c;
            float v;
            if (CONCAT_RELU_IN) {
                // k-tile never straddles DH (2048 % 16 == 0) -> uniform branch
                v = (gk < DH) ? A0[(size_t)gr * DH + gk]
                              : A1[(size_t)gr * DH + (gk - DH)];
                v = v > 0.f ? v : 0.f;
            } else {
                v = A0[(size_t)gr * K + gk];
            }
            As[c][r] = v;
        }
        // --- stage B tile (BK x BN) ---
        #pragma unroll
        for (int i = 0; i < 4; ++i) {
            const int r = (tid >> 6) + i * 4;    // 0..15 (k)
            const int c = tid & 63;              // 0..63 (n)
            Bs[r][c] = W[(size_t)(k0 + r) * N + col0 + c];
        }
        __syncthreads();

        // --- 4x4 outer-product accumulate, float4 LDS reads ---
        #pragma unroll
        for (int k = 0; k < BK; ++k) {
            const float4 a = *(const float4*)&As[k][ty * 4];
            const float4 b = *(const float4*)&Bs[k][tx * 4];
            const float av[4] = {a.x, a.y, a.z, a.w};
            const float bv[4] = {b.x, b.y, b.z, b.w};
            #pragma unroll
            for (int i = 0; i < 4; ++i)
                #pragma unroll
                for (int j = 0; j < 4; ++j)
                    acc[i][j] = fmaf(av[i], bv[j], acc[i][j]);
        }
        __syncthreads();
    }

    // --- epilogue: +bias, optional relu, float4 stores ---
    const float4 bb = *(const float4*)&bias[col0 + tx * 4];
    const float bv[4] = {bb.x, bb.y, bb.z, bb.w};
    #pragma unroll
    for (int i = 0; i < 4; ++i) {
        const int gr = row0 + ty * 4 + i;
        float o[4];
        #pragma unroll
        for (int j = 0; j < 4; ++j) {
            float t = acc[i][j] + bv[j];
            if (RELU_OUT) t = t > 0.f ? t : 0.f;
            o[j] = t;
        }
        float4 ov = {o[0], o[1], o[2], o[3]};
        *(float4*)&out[(size_t)gr * N + col0 + tx * 4] = ov;
    }
}

// scores[b,l] = -||relu(label[l] - emb[b])||_2
// One block per batch row; emb row in LDS; each wave owns labels l = wave, wave+4, ...
__global__ __launch_bounds__(256)
void score_kernel(const float* __restrict__ emb, const float* __restrict__ labels,
                  float* __restrict__ out)
{
    __shared__ __align__(16) float es[DO];
    const int b   = blockIdx.x;
    const int tid = threadIdx.x;

    *(float4*)&es[tid * 4] = *(const float4*)&emb[(size_t)b * DO + tid * 4];
    __syncthreads();

    const int wave = tid >> 6;
    const int lane = tid & 63;

    for (int l = wave; l < NL; l += 4) {
        const float* lab = labels + (size_t)l * DO;
        float s = 0.f;
        #pragma unroll
        for (int i = 0; i < 4; ++i) {
            const int d = i * 256 + lane * 4;
            const float4 lv = *(const float4*)&lab[d];
            const float4 ev = *(const float4*)&es[d];
            float dx = lv.x - ev.x; dx = dx > 0.f ? dx : 0.f; s = fmaf(dx, dx, s);
            float dy = lv.y - ev.y; dy = dy > 0.f ? dy : 0.f; s = fmaf(dy, dy, s);
            float dz = lv.z - ev.z; dz = dz > 0.f ? dz : 0.f; s = fmaf(dz, dz, s);
            float dw = lv.w - ev.w; dw = dw > 0.f ? dw : 0.f; s = fmaf(dw, dw, s);
        }
        #pragma unroll
        for (int off = 32; off > 0; off >>= 1)
            s += __shfl_down(s, off, 64);
        if (lane == 0) out[(size_t)b * NL + l] = -sqrtf(s);
    }
}

extern "C" void kernel_launch(void* const* d_in, const int* in_sizes, int n_in,
                              void* d_out, int out_size, void* d_ws, size_t ws_size,
                              hipStream_t stream) {
    const float* sbj  = (const float*)d_in[0];
    const float* obj  = (const float*)d_in[1];
    const float* W1   = (const float*)d_in[2];
    const float* b1   = (const float*)d_in[3];
    const float* W2   = (const float*)d_in[4];
    const float* b2   = (const float*)d_in[5];
    const float* labs = (const float*)d_in[6];
    float* scores = (float*)d_out;

    float* H = (float*)d_ws;              // [B, DO] = relu(hidden)
    float* E = H + (size_t)Bn * DO;       // [B, DO] = emb

    dim3 blk(256);
    dim3 g1(DO / BN, Bn / BM);

    // H = relu( relu(cat(sbj,obj)) @ W1 + b1 )
    gemm_kernel<true, true><<<g1, blk, 0, stream>>>(sbj, obj, W1, b1, H, Bn, DO, K1);
    // E = H @ W2 + b2
    gemm_kernel<false, false><<<g1, blk, 0, stream>>>(H, nullptr, W2, b2, E, Bn, DO, DO);
    // scores[b,l] = -||relu(labs[l] - E[b])||
    score_kernel<<<dim3(Bn), blk, 0, stream>>>(E, labs, scores);
}

// Round 2
// 175.934 us; speedup vs baseline: 2.7808x; 2.7808x over previous
//
#include <hip/hip_runtime.h>
#include <math.h>

constexpr int Bn = 1024, DH = 2048, K1 = 4096, DO = 1024, NL = 128;

typedef __bf16 bf16x8 __attribute__((ext_vector_type(8)));
typedef short  s16x8  __attribute__((ext_vector_type(8)));
typedef float  f32x4  __attribute__((ext_vector_type(4)));

__device__ __forceinline__ unsigned short f2bf(float f) {
  union { float f; unsigned u; } v; v.f = f;
  unsigned r = v.u + 0x7FFFu + ((v.u >> 16) & 1u);  // round-to-nearest-even
  return (unsigned short)(r >> 16);
}

// ---------- convert kernels ----------

// out[m][k] = bf16(relu(concat(sbj,obj)[m][k])), out is [1024][4096]
__global__ __launch_bounds__(256)
void concat_relu_bf16(const float* __restrict__ sbj, const float* __restrict__ obj,
                      unsigned short* __restrict__ out) {
  const int t = blockIdx.x * 256 + threadIdx.x;   // 524288 threads, 8 elems each
  const int m = t >> 9;
  const int k = (t & 511) << 3;
  const float* src = (k < DH) ? sbj + (size_t)m * DH + k
                              : obj + (size_t)m * DH + (k - DH);
  const float4 a = ((const float4*)src)[0];
  const float4 b = ((const float4*)src)[1];
  uint4 o;
  o.x = (unsigned)f2bf(fmaxf(a.x, 0.f)) | ((unsigned)f2bf(fmaxf(a.y, 0.f)) << 16);
  o.y = (unsigned)f2bf(fmaxf(a.z, 0.f)) | ((unsigned)f2bf(fmaxf(a.w, 0.f)) << 16);
  o.z = (unsigned)f2bf(fmaxf(b.x, 0.f)) | ((unsigned)f2bf(fmaxf(b.y, 0.f)) << 16);
  o.w = (unsigned)f2bf(fmaxf(b.z, 0.f)) | ((unsigned)f2bf(fmaxf(b.w, 0.f)) << 16);
  *(uint4*)&out[(size_t)m * K1 + k] = o;
}

// out[c][r] = bf16(in[r][c]); in fp32 [R][C] -> out bf16 [C][R]. 64x64 LDS tiles.
__global__ __launch_bounds__(256)
void transp_bf16(const float* __restrict__ in, unsigned short* __restrict__ out,
                 int R, int C) {
  __shared__ float tl[64][65];
  const int tid = threadIdx.x;
  const int r0 = blockIdx.y * 64, c0 = blockIdx.x * 64;
  {
    const int rr = tid >> 4, cc = (tid & 15) * 4;
    #pragma unroll
    for (int i = 0; i < 4; ++i) {
      const float4 v = *(const float4*)&in[(size_t)(r0 + rr + i * 16) * C + c0 + cc];
      tl[rr + i * 16][cc + 0] = v.x; tl[rr + i * 16][cc + 1] = v.y;
      tl[rr + i * 16][cc + 2] = v.z; tl[rr + i * 16][cc + 3] = v.w;
    }
  }
  __syncthreads();
  {
    const int r4 = (tid & 15) * 4;
    #pragma unroll
    for (int i = 0; i < 4; ++i) {
      const int cr = i * 16 + (tid >> 4);
      uint2 o;
      o.x = (unsigned)f2bf(tl[r4 + 0][cr]) | ((unsigned)f2bf(tl[r4 + 1][cr]) << 16);
      o.y = (unsigned)f2bf(tl[r4 + 2][cr]) | ((unsigned)f2bf(tl[r4 + 3][cr]) << 16);
      *(uint2*)&out[(size_t)(c0 + cr) * R + r0 + r4] = o;
    }
  }
}

// ---------- MFMA GEMM ----------
// out[M][N] = act(A @ Bt^T + bias); A bf16 [M][K], Bt bf16 [N][K] (pre-transposed W).
// Block: 256 thr = 4 waves, tile 64x64, BK=256 per outer iter, wave w owns
// k-chunk [w*64, w*64+64) of each BK block (split-K across waves, LDS tree-reduce).
// LDS layout: [row][kc-chunk-of-8], with kc XOR-swizzled by (row&7) so that
// global_load_lds staging stays lane-contiguous AND ds_read_b128 frags are
// conflict-free (2-way only).
template <int K, bool RELU, typename OUTT>
__global__ __launch_bounds__(256, 1)
void mfma_gemm64(const unsigned short* __restrict__ A,
                 const unsigned short* __restrict__ Bt,
                 const float* __restrict__ bias,
                 OUTT* __restrict__ out, int M, int N) {
  __shared__ __align__(16) unsigned short Asm[64 * 256];  // 32 KB
  __shared__ __align__(16) unsigned short Bsm[64 * 256];  // 32 KB

  const int tid = threadIdx.x;
  const int w = tid >> 6, l = tid & 63;
  const int m0 = blockIdx.y * 64, n0 = blockIdx.x * 64;

  f32x4 acc[4][4] = {};

  for (int ko = 0; ko < K; ko += 256) {
    // ---- stage A tile [64m][256k] and B tile [64n][256k], 16B/lane DMA ----
    #pragma unroll
    for (int i = 0; i < 8; ++i) {
      const int c = i * 256 + tid;
      const int m = c >> 5, kc = c & 31;
      const int kcg = (kc & 24) | ((kc & 7) ^ (m & 7));
      const unsigned short* ga = A + (size_t)(m0 + m) * K + ko + kcg * 8;
      __builtin_amdgcn_global_load_lds(
          (const __attribute__((address_space(1))) unsigned int*)ga,
          (__attribute__((address_space(3))) unsigned int*)&Asm[(i * 256 + w * 64) * 8],
          16, 0, 0);
    }
    #pragma unroll
    for (int i = 0; i < 8; ++i) {
      const int c = i * 256 + tid;
      const int n = c >> 5, kc = c & 31;
      const int kcg = (kc & 24) | ((kc & 7) ^ (n & 7));
      const unsigned short* gb = Bt + (size_t)(n0 + n) * K + ko + kcg * 8;
      __builtin_amdgcn_global_load_lds(
          (const __attribute__((address_space(1))) unsigned int*)gb,
          (__attribute__((address_space(3))) unsigned int*)&Bsm[(i * 256 + w * 64) * 8],
          16, 0, 0);
    }
    __syncthreads();

    // ---- compute: wave w handles k in [w*64, w*64+64) of this BK block ----
    #pragma unroll
    for (int s = 0; s < 2; ++s) {
      const int kcq = w * 8 + s * 4 + (l >> 4);  // logical k-chunk 0..31
      bf16x8 af[4], bfr[4];
      #pragma unroll
      for (int i = 0; i < 4; ++i) {
        const int r = i * 16 + (l & 15);  // m (for A) / n (for B) local index
        const int kca = (kcq & 24) | ((kcq & 7) ^ (r & 7));
        af[i]  = __builtin_bit_cast(bf16x8, *(const s16x8*)&Asm[r * 256 + kca * 8]);
        bfr[i] = __builtin_bit_cast(bf16x8, *(const s16x8*)&Bsm[r * 256 + kca * 8]);
      }
      #pragma unroll
      for (int i = 0; i < 4; ++i)
        #pragma unroll
        for (int j = 0; j < 4; ++j)
          acc[i][j] = __builtin_amdgcn_mfma_f32_16x16x32_bf16(af[i], bfr[j], acc[i][j], 0, 0, 0);
    }
    __syncthreads();
  }

  // ---- cross-wave split-K reduction (tree into wave 0), reusing Asm ----
  float* red = (float*)Asm;  // 8192 floats = two 16 KB regions
  if (w == 1 || w == 3) {
    float* dst = red + (w >> 1) * 4096;
    #pragma unroll
    for (int i = 0; i < 4; ++i)
      #pragma unroll
      for (int j = 0; j < 4; ++j)
        *(f32x4*)&dst[((i * 4 + j) * 64 + l) * 4] = acc[i][j];
  }
  __syncthreads();
  if (w == 0 || w == 2) {
    const float* src = red + (w >> 1) * 4096;
    #pragma unroll
    for (int i = 0; i < 4; ++i)
      #pragma unroll
      for (int j = 0; j < 4; ++j)
        acc[i][j] += *(const f32x4*)&src[((i * 4 + j) * 64 + l) * 4];
  }
  __syncthreads();
  if (w == 2) {
    #pragma unroll
    for (int i = 0; i < 4; ++i)
      #pragma unroll
      for (int j = 0; j < 4; ++j)
        *(f32x4*)&red[((i * 4 + j) * 64 + l) * 4] = acc[i][j];
  }
  __syncthreads();
  if (w != 0) return;
  #pragma unroll
  for (int i = 0; i < 4; ++i)
    #pragma unroll
    for (int j = 0; j < 4; ++j)
      acc[i][j] += *(const f32x4*)&red[((i * 4 + j) * 64 + l) * 4];

  // ---- epilogue (wave 0): +bias, relu?, store. C/D: col=l&15, row=(l>>4)*4+r ----
  #pragma unroll
  for (int j = 0; j < 4; ++j) {
    const int n = n0 + j * 16 + (l & 15);
    const float bb = bias[n];
    #pragma unroll
    for (int i = 0; i < 4; ++i) {
      #pragma unroll
      for (int r = 0; r < 4; ++r) {
        const int m = m0 + i * 16 + (l >> 4) * 4 + r;
        float v = acc[i][j][r] + bb;
        if (RELU) v = fmaxf(v, 0.f);
        if constexpr (sizeof(OUTT) == 2)
          out[(size_t)m * N + n] = (OUTT)f2bf(v);
        else
          out[(size_t)m * N + n] = (OUTT)v;
      }
    }
  }
}

// ---------- scores ----------
// scores[b,l] = -||relu(label[l]-emb[b])||_2 ; 4 batch rows per block for label reuse.
__global__ __launch_bounds__(256)
void score4(const float* __restrict__ emb, const float* __restrict__ labels,
            float* __restrict__ out) {
  __shared__ __align__(16) float es[4][DO];
  const int b0 = blockIdx.x * 4;
  const int tid = threadIdx.x;
  #pragma unroll
  for (int i = 0; i < 4; ++i) {
    const int idx = i * 256 + tid;            // float4 index over 4 rows
    const int r = idx >> 8, c = (idx & 255) * 4;
    *(float4*)&es[r][c] = *(const float4*)&emb[(size_t)(b0 + r) * DO + c];
  }
  __syncthreads();
  const int w = tid >> 6, l = tid & 63;
  for (int lab = w; lab < NL; lab += 4) {
    const float* lp = labels + (size_t)lab * DO;
    float s0 = 0.f, s1 = 0.f, s2 = 0.f, s3 = 0.f;
    #pragma unroll
    for (int i = 0; i < 4; ++i) {
      const int d = i * 256 + l * 4;
      const float4 lv = *(const float4*)&lp[d];
      const float4 e0 = *(const float4*)&es[0][d];
      const float4 e1 = *(const float4*)&es[1][d];
      const float4 e2 = *(const float4*)&es[2][d];
      const float4 e3 = *(const float4*)&es[3][d];
      float t;
      t = fmaxf(lv.x - e0.x, 0.f); s0 = fmaf(t, t, s0);
      t = fmaxf(lv.y - e0.y, 0.f); s0 = fmaf(t, t, s0);
      t = fmaxf(lv.z - e0.z, 0.f); s0 = fmaf(t, t, s0);
      t = fmaxf(lv.w - e0.w, 0.f); s0 = fmaf(t, t, s0);
      t = fmaxf(lv.x - e1.x, 0.f); s1 = fmaf(t, t, s1);
      t = fmaxf(lv.y - e1.y, 0.f); s1 = fmaf(t, t, s1);
      t = fmaxf(lv.z - e1.z, 0.f); s1 = fmaf(t, t, s1);
      t = fmaxf(lv.w - e1.w, 0.f); s1 = fmaf(t, t, s1);
      t = fmaxf(lv.x - e2.x, 0.f); s2 = fmaf(t, t, s2);
      t = fmaxf(lv.y - e2.y, 0.f); s2 = fmaf(t, t, s2);
      t = fmaxf(lv.z - e2.z, 0.f); s2 = fmaf(t, t, s2);
      t = fmaxf(lv.w - e2.w, 0.f); s2 = fmaf(t, t, s2);
      t = fmaxf(lv.x - e3.x, 0.f); s3 = fmaf(t, t, s3);
      t = fmaxf(lv.y - e3.y, 0.f); s3 = fmaf(t, t, s3);
      t = fmaxf(lv.z - e3.z, 0.f); s3 = fmaf(t, t, s3);
      t = fmaxf(lv.w - e3.w, 0.f); s3 = fmaf(t, t, s3);
    }
    #pragma unroll
    for (int off = 32; off > 0; off >>= 1) {
      s0 += __shfl_down(s0, off, 64);
      s1 += __shfl_down(s1, off, 64);
      s2 += __shfl_down(s2, off, 64);
      s3 += __shfl_down(s3, off, 64);
    }
    if (l == 0) {
      out[(size_t)(b0 + 0) * NL + lab] = -sqrtf(s0);
      out[(size_t)(b0 + 1) * NL + lab] = -sqrtf(s1);
      out[(size_t)(b0 + 2) * NL + lab] = -sqrtf(s2);
      out[(size_t)(b0 + 3) * NL + lab] = -sqrtf(s3);
    }
  }
}

extern "C" void kernel_launch(void* const* d_in, const int* in_sizes, int n_in,
                              void* d_out, int out_size, void* d_ws, size_t ws_size,
                              hipStream_t stream) {
  const float* sbj  = (const float*)d_in[0];
  const float* obj  = (const float*)d_in[1];
  const float* W1   = (const float*)d_in[2];
  const float* b1   = (const float*)d_in[3];
  const float* W2   = (const float*)d_in[4];
  const float* b2   = (const float*)d_in[5];
  const float* labs = (const float*)d_in[6];
  float* scores = (float*)d_out;

  char* ws = (char*)d_ws;
  unsigned short* Abf = (unsigned short*)(ws);                    // 8 MB [1024][4096]
  unsigned short* W1t = (unsigned short*)(ws + (8u << 20));       // 8 MB [1024][4096]
  unsigned short* W2t = (unsigned short*)(ws + (16u << 20));      // 2 MB [1024][1024]
  unsigned short* H   = (unsigned short*)(ws + (18u << 20));      // 2 MB [1024][1024]
  float*          E   = (float*)(ws + (20u << 20));               // 4 MB [1024][1024]

  dim3 blk(256);
  // converts
  concat_relu_bf16<<<dim3(2048), blk, 0, stream>>>(sbj, obj, Abf);
  transp_bf16<<<dim3(DO / 64, K1 / 64), blk, 0, stream>>>(W1, W1t, K1, DO);
  transp_bf16<<<dim3(DO / 64, DO / 64), blk, 0, stream>>>(W2, W2t, DO, DO);
  // H = relu(A @ W1 + b1)  (bf16 out)
  mfma_gemm64<K1, true, unsigned short><<<dim3(16, 16), blk, 0, stream>>>(
      Abf, W1t, b1, H, Bn, DO);
  // E = H @ W2 + b2  (fp32 out)
  mfma_gemm64<DO, false, float><<<dim3(16, 16), blk, 0, stream>>>(
      H, W2t, b2, E, Bn, DO);
  // scores
  score4<<<dim3(Bn / 4), blk, 0, stream>>>(E, labs, scores);
}